// Round 2
// baseline (4261.876 us; speedup 1.0000x reference)
//
#include <hip/hip_runtime.h>
#include <hip/hip_bf16.h>

typedef __bf16 bf16_t;
typedef __bf16 bf16x8 __attribute__((ext_vector_type(8)));
typedef float floatx4 __attribute__((ext_vector_type(4)));

#define D_MODEL 768
#define N_HEADS 12
#define DK 64
#define SEQ 1024
#define BATCH 2
#define NROWS (BATCH * SEQ)
#define FFN 3072
#define VOCAB 32000
#define N_LAYERS 4
#define LN_EPS 1e-5f

// ---------------------------------------------------------------- reductions
__device__ __forceinline__ float block_reduce_256(float v, bool is_max, float* sb) {
#pragma unroll
    for (int off = 32; off > 0; off >>= 1) {
        float o = __shfl_down(v, off, 64);
        v = is_max ? fmaxf(v, o) : (v + o);
    }
    int lane = threadIdx.x & 63, wid = threadIdx.x >> 6;
    if (lane == 0) sb[wid] = v;
    __syncthreads();
    float r = is_max ? fmaxf(fmaxf(sb[0], sb[1]), fmaxf(sb[2], sb[3]))
                     : (sb[0] + sb[1]) + (sb[2] + sb[3]);
    __syncthreads();
    return r;
}

// ---------------------------------------------------------------- embedding
__global__ __launch_bounds__(256) void embed_kernel(const int* __restrict__ x,
                                                    const float* __restrict__ tok,
                                                    const float* __restrict__ pos,
                                                    float* __restrict__ h) {
    int row = blockIdx.x;               // 0..NROWS-1
    int s = row & (SEQ - 1);
    int t = x[row];
    const float* te = tok + (size_t)t * D_MODEL;
    const float* pe = pos + (size_t)s * D_MODEL;
    float* out = h + (size_t)row * D_MODEL;
    int tid = threadIdx.x;
    out[tid]       = te[tid]       + pe[tid];
    out[tid + 256] = te[tid + 256] + pe[tid + 256];
    out[tid + 512] = te[tid + 512] + pe[tid + 512];
}

// ---------------------------------------------------------------- layernorm
__global__ __launch_bounds__(256) void ln_kernel(const float* __restrict__ h,
                                                 const float* __restrict__ g,
                                                 const float* __restrict__ b,
                                                 bf16_t* __restrict__ y) {
    __shared__ float sb[4];
    int row = blockIdx.x;
    const float* xr = h + (size_t)row * D_MODEL;
    int t = threadIdx.x;
    float v0 = xr[t], v1 = xr[t + 256], v2 = xr[t + 512];
    float s  = block_reduce_256(v0 + v1 + v2, false, sb);
    float s2 = block_reduce_256(v0 * v0 + v1 * v1 + v2 * v2, false, sb);
    float mu  = s * (1.0f / D_MODEL);
    float var = s2 * (1.0f / D_MODEL) - mu * mu;
    float inv = rsqrtf(var + LN_EPS);
    bf16_t* yr = y + (size_t)row * D_MODEL;
    yr[t]       = (bf16_t)((v0 - mu) * inv * g[t]       + b[t]);
    yr[t + 256] = (bf16_t)((v1 - mu) * inv * g[t + 256] + b[t + 256]);
    yr[t + 512] = (bf16_t)((v2 - mu) * inv * g[t + 512] + b[t + 512]);
}

// ---------------------------------------------------------------- GEMM: C = A(MxK,bf16) . W(NxK,fp32)^T  (+bias)(+relu)(+res)
// 64x64 tile, BK=32, mfma_f32_16x16x32_bf16. fp32 accumulation. W converted
// fp32->bf16 during LDS staging.
template <typename OutT, bool RELU, bool HAS_BIAS, bool HAS_RES>
__global__ __launch_bounds__(256) void gemm_bt(const bf16_t* __restrict__ A,
                                               const float* __restrict__ W,
                                               const float* __restrict__ bias,
                                               const float* __restrict__ res,
                                               OutT* __restrict__ C,
                                               int M, int N, int K) {
    const int LDR = 40;                      // padded row stride in bf16 (80 B, 16B-aligned)
    __shared__ bf16_t As[64 * LDR];
    __shared__ bf16_t Bs[64 * LDR];
    const int m0 = blockIdx.y * 64;
    const int n0 = blockIdx.x * 64;
    const int tid  = threadIdx.x;
    const int wave = tid >> 6;
    const int lane = tid & 63;
    const int q    = lane >> 4;              // quad 0..3
    const int ln16 = lane & 15;

    floatx4 acc[4] = {{0.f, 0.f, 0.f, 0.f}, {0.f, 0.f, 0.f, 0.f},
                      {0.f, 0.f, 0.f, 0.f}, {0.f, 0.f, 0.f, 0.f}};

    const int srow = tid >> 2;               // 0..63
    const int scol = (tid & 3) * 8;          // 0,8,16,24
    const bf16_t* Aptr = A + (size_t)(m0 + srow) * K + scol;
    const float*  Wptr = W + (size_t)(n0 + srow) * K + scol;

    for (int k0 = 0; k0 < K; k0 += 32) {
        *(uint4*)(&As[srow * LDR + scol]) = *(const uint4*)(Aptr + k0);
        float4 w0 = *(const float4*)(Wptr + k0);
        float4 w1 = *(const float4*)(Wptr + k0 + 4);
        bf16x8 wb;
        wb[0] = (bf16_t)w0.x; wb[1] = (bf16_t)w0.y; wb[2] = (bf16_t)w0.z; wb[3] = (bf16_t)w0.w;
        wb[4] = (bf16_t)w1.x; wb[5] = (bf16_t)w1.y; wb[6] = (bf16_t)w1.z; wb[7] = (bf16_t)w1.w;
        *(bf16x8*)(&Bs[srow * LDR + scol]) = wb;
        __syncthreads();
        const bf16x8 a = *(const bf16x8*)(&As[(wave * 16 + ln16) * LDR + q * 8]);
#pragma unroll
        for (int nt = 0; nt < 4; nt++) {
            const bf16x8 b = *(const bf16x8*)(&Bs[(nt * 16 + ln16) * LDR + q * 8]);
            acc[nt] = __builtin_amdgcn_mfma_f32_16x16x32_bf16(a, b, acc[nt], 0, 0, 0);
        }
        __syncthreads();
    }

#pragma unroll
    for (int nt = 0; nt < 4; nt++) {
        const int n = n0 + nt * 16 + ln16;
        float bv = 0.f;
        if constexpr (HAS_BIAS) bv = bias[n];
#pragma unroll
        for (int r = 0; r < 4; r++) {
            const int m = m0 + wave * 16 + q * 4 + r;
            float v = acc[nt][r] + bv;
            if constexpr (RELU) v = fmaxf(v, 0.f);
            if constexpr (HAS_RES) v += res[(size_t)m * N + n];
            C[(size_t)m * N + n] = (OutT)v;
        }
    }
}

// ---------------------------------------------------------------- attention (one block per (b,h,q-row))
__global__ __launch_bounds__(256) void attn_kernel(const float* __restrict__ Q,
                                                   const float* __restrict__ K,
                                                   const float* __restrict__ V,
                                                   bf16_t* __restrict__ ctx) {
    __shared__ float qs[DK];
    __shared__ float p[SEQ];
    __shared__ float sb[4];
    __shared__ float red[4][DK];

    const int s  = blockIdx.x;
    const int bh = blockIdx.y;
    const int b  = bh / N_HEADS;
    const int hh = bh - b * N_HEADS;
    const int tid = threadIdx.x;
    const size_t rowbase = (size_t)(b * SEQ) * D_MODEL + hh * DK;

    if (tid < DK) qs[tid] = Q[rowbase + (size_t)s * D_MODEL + tid];
    __syncthreads();

    const float scale = rsqrtf((float)DK);
    float lmax = -INFINITY;
    for (int j = tid; j <= s; j += 256) {
        const float* krow = K + rowbase + (size_t)j * D_MODEL;
        float d = 0.f;
#pragma unroll
        for (int e = 0; e < DK; e += 4) {
            float4 kv = *(const float4*)(krow + e);
            d += qs[e] * kv.x + qs[e + 1] * kv.y + qs[e + 2] * kv.z + qs[e + 3] * kv.w;
        }
        d *= scale;
        p[j] = d;
        lmax = fmaxf(lmax, d);
    }
    float gmax = block_reduce_256(lmax, true, sb);

    float lsum = 0.f;
    for (int j = tid; j <= s; j += 256) {
        float e = __expf(p[j] - gmax);
        p[j] = e;
        lsum += e;
    }
    float gsum = block_reduce_256(lsum, false, sb);   // trailing __syncthreads -> p[] visible to all
    const float inv = 1.0f / gsum;

    const int d    = tid & 63;
    const int part = tid >> 6;
    float accv = 0.f;
    for (int j = part; j <= s; j += 4) {
        accv += p[j] * V[rowbase + (size_t)j * D_MODEL + d];
    }
    red[part][d] = accv;
    __syncthreads();
    if (tid < DK) {
        float v = (red[0][tid] + red[1][tid] + red[2][tid] + red[3][tid]) * inv;
        ctx[rowbase + (size_t)s * D_MODEL + tid] = (bf16_t)v;
    }
}

// ---------------------------------------------------------------- launch
extern "C" void kernel_launch(void* const* d_in, const int* in_sizes, int n_in,
                              void* d_out, int out_size, void* d_ws, size_t ws_size,
                              hipStream_t stream) {
    const int*   x    = (const int*)d_in[0];
    const float* tok  = (const float*)d_in[1];
    const float* pos  = (const float*)d_in[2];
    const float* Wq   = (const float*)d_in[3];
    const float* bq   = (const float*)d_in[4];
    const float* Wk   = (const float*)d_in[5];
    const float* bk   = (const float*)d_in[6];
    const float* Wv   = (const float*)d_in[7];
    const float* bv   = (const float*)d_in[8];
    const float* Wo   = (const float*)d_in[9];
    const float* bo   = (const float*)d_in[10];
    const float* W1   = (const float*)d_in[11];
    const float* b1   = (const float*)d_in[12];
    const float* W2   = (const float*)d_in[13];
    const float* b2   = (const float*)d_in[14];
    const float* ln1g = (const float*)d_in[15];
    const float* ln1b = (const float*)d_in[16];
    const float* ln2g = (const float*)d_in[17];
    const float* ln2b = (const float*)d_in[18];
    const float* lnfg = (const float*)d_in[19];
    const float* lnfb = (const float*)d_in[20];

    char* ws = (char*)d_ws;
    // workspace layout (bytes)
    const size_t OFF_H   = 0;                               // fp32 [2048,768]   6.29 MB
    const size_t OFF_Y   = 6291456;                         // bf16 [2048,768]   3.15 MB
    const size_t OFF_Q   = OFF_Y + 3145728;                 // fp32 [2048,768]
    const size_t OFF_K   = OFF_Q + 6291456;                 // fp32 [2048,768]
    const size_t OFF_V   = OFF_K + 6291456;                 // fp32 [2048,768]
    const size_t OFF_CTX = OFF_V + 6291456;                 // bf16 [2048,768]
    const size_t OFF_FF  = OFF_Q;                           // bf16 [2048,3072] (aliases dead q/k)

    float*  h    = (float*)(ws + OFF_H);
    bf16_t* y    = (bf16_t*)(ws + OFF_Y);
    float*  qb   = (float*)(ws + OFF_Q);
    float*  kb   = (float*)(ws + OFF_K);
    float*  vb   = (float*)(ws + OFF_V);
    bf16_t* ctx  = (bf16_t*)(ws + OFF_CTX);
    bf16_t* ff   = (bf16_t*)(ws + OFF_FF);
    float*  outp = (float*)d_out;

    embed_kernel<<<NROWS, 256, 0, stream>>>(x, tok, pos, h);

    const dim3 g768(D_MODEL / 64, NROWS / 64);   // 12 x 32
    const dim3 gffn(FFN / 64, NROWS / 64);       // 48 x 32
    const dim3 gvoc(VOCAB / 64, NROWS / 64);     // 500 x 32
    const dim3 gattn(SEQ, BATCH * N_HEADS);      // 1024 x 24

    for (int l = 0; l < N_LAYERS; l++) {
        const float* Wq_l = Wq + (size_t)l * D_MODEL * D_MODEL;
        const float* Wk_l = Wk + (size_t)l * D_MODEL * D_MODEL;
        const float* Wv_l = Wv + (size_t)l * D_MODEL * D_MODEL;
        const float* Wo_l = Wo + (size_t)l * D_MODEL * D_MODEL;
        const float* W1_l = W1 + (size_t)l * FFN * D_MODEL;
        const float* W2_l = W2 + (size_t)l * D_MODEL * FFN;

        ln_kernel<<<NROWS, 256, 0, stream>>>(h, ln1g + l * D_MODEL, ln1b + l * D_MODEL, y);

        gemm_bt<float, false, true, false><<<g768, 256, 0, stream>>>(
            y, Wq_l, bq + l * D_MODEL, nullptr, qb, NROWS, D_MODEL, D_MODEL);
        gemm_bt<float, false, true, false><<<g768, 256, 0, stream>>>(
            y, Wk_l, bk + l * D_MODEL, nullptr, kb, NROWS, D_MODEL, D_MODEL);
        gemm_bt<float, false, true, false><<<g768, 256, 0, stream>>>(
            y, Wv_l, bv + l * D_MODEL, nullptr, vb, NROWS, D_MODEL, D_MODEL);

        attn_kernel<<<gattn, 256, 0, stream>>>(qb, kb, vb, ctx);

        // h = h + ctx @ Wo^T + bo   (in-place residual)
        gemm_bt<float, false, true, true><<<g768, 256, 0, stream>>>(
            ctx, Wo_l, bo + l * D_MODEL, h, h, NROWS, D_MODEL, D_MODEL);

        ln_kernel<<<NROWS, 256, 0, stream>>>(h, ln2g + l * D_MODEL, ln2b + l * D_MODEL, y);

        // ff = relu(y @ W1^T + b1)
        gemm_bt<bf16_t, true, true, false><<<gffn, 256, 0, stream>>>(
            y, W1_l, b1 + l * FFN, nullptr, ff, NROWS, FFN, D_MODEL);

        // h = h + ff @ W2^T + b2
        gemm_bt<float, false, true, true><<<g768, 256, 0, stream>>>(
            ff, W2_l, b2 + l * D_MODEL, h, h, NROWS, D_MODEL, FFN);
    }

    ln_kernel<<<NROWS, 256, 0, stream>>>(h, lnfg, lnfb, y);

    // logits = y @ tok_emb^T  -> fp32 out [2048, 32000]
    gemm_bt<float, false, false, false><<<gvoc, 256, 0, stream>>>(
        y, tok, nullptr, nullptr, outp, NROWS, VOCAB, D_MODEL);
}

// Round 3
// 1810.791 us; speedup vs baseline: 2.3536x; 2.3536x over previous
//
#include <hip/hip_runtime.h>
#include <hip/hip_bf16.h>

typedef __bf16 bf16_t;
typedef __bf16 bf16x8 __attribute__((ext_vector_type(8)));
typedef float floatx4 __attribute__((ext_vector_type(4)));

#define D_MODEL 768
#define N_HEADS 12
#define DK 64
#define SEQ 1024
#define BATCH 2
#define NROWS (BATCH * SEQ)
#define FFN 3072
#define VOCAB 32000
#define N_LAYERS 4
#define LN_EPS 1e-5f

// ---------------------------------------------------------------- reductions
__device__ __forceinline__ float block_reduce_256(float v, bool is_max, float* sb) {
#pragma unroll
    for (int off = 32; off > 0; off >>= 1) {
        float o = __shfl_down(v, off, 64);
        v = is_max ? fmaxf(v, o) : (v + o);
    }
    int lane = threadIdx.x & 63, wid = threadIdx.x >> 6;
    if (lane == 0) sb[wid] = v;
    __syncthreads();
    float r = is_max ? fmaxf(fmaxf(sb[0], sb[1]), fmaxf(sb[2], sb[3]))
                     : (sb[0] + sb[1]) + (sb[2] + sb[3]);
    __syncthreads();
    return r;
}

// ---------------------------------------------------------------- embedding
__global__ __launch_bounds__(256) void embed_kernel(const int* __restrict__ x,
                                                    const float* __restrict__ tok,
                                                    const float* __restrict__ pos,
                                                    float* __restrict__ h) {
    int row = blockIdx.x;
    int s = row & (SEQ - 1);
    int t = x[row];
    const float* te = tok + (size_t)t * D_MODEL;
    const float* pe = pos + (size_t)s * D_MODEL;
    float* out = h + (size_t)row * D_MODEL;
    int tid = threadIdx.x;
    out[tid]       = te[tid]       + pe[tid];
    out[tid + 256] = te[tid + 256] + pe[tid + 256];
    out[tid + 512] = te[tid + 512] + pe[tid + 512];
}

// ---------------------------------------------------------------- layernorm
__global__ __launch_bounds__(256) void ln_kernel(const float* __restrict__ h,
                                                 const float* __restrict__ g,
                                                 const float* __restrict__ b,
                                                 bf16_t* __restrict__ y) {
    __shared__ float sb[4];
    int row = blockIdx.x;
    const float* xr = h + (size_t)row * D_MODEL;
    int t = threadIdx.x;
    float v0 = xr[t], v1 = xr[t + 256], v2 = xr[t + 512];
    float s  = block_reduce_256(v0 + v1 + v2, false, sb);
    float s2 = block_reduce_256(v0 * v0 + v1 * v1 + v2 * v2, false, sb);
    float mu  = s * (1.0f / D_MODEL);
    float var = s2 * (1.0f / D_MODEL) - mu * mu;
    float inv = rsqrtf(var + LN_EPS);
    bf16_t* yr = y + (size_t)row * D_MODEL;
    yr[t]       = (bf16_t)((v0 - mu) * inv * g[t]       + b[t]);
    yr[t + 256] = (bf16_t)((v1 - mu) * inv * g[t + 256] + b[t + 256]);
    yr[t + 512] = (bf16_t)((v2 - mu) * inv * g[t + 512] + b[t + 512]);
}

// ---------------------------------------------------------------- GEMM: C = A(MxK,bf16) . W(NxK,fp32)^T  (+bias)(+relu)(+res)
template <typename OutT, bool RELU, bool HAS_BIAS, bool HAS_RES>
__global__ __launch_bounds__(256) void gemm_bt(const bf16_t* __restrict__ A,
                                               const float* __restrict__ W,
                                               const float* __restrict__ bias,
                                               const float* __restrict__ res,
                                               OutT* __restrict__ C,
                                               int M, int N, int K) {
    const int LDR = 40;
    __shared__ bf16_t As[64 * LDR];
    __shared__ bf16_t Bs[64 * LDR];
    const int m0 = blockIdx.y * 64;
    const int n0 = blockIdx.x * 64;
    const int tid  = threadIdx.x;
    const int wave = tid >> 6;
    const int lane = tid & 63;
    const int q    = lane >> 4;
    const int ln16 = lane & 15;

    floatx4 acc[4] = {{0.f, 0.f, 0.f, 0.f}, {0.f, 0.f, 0.f, 0.f},
                      {0.f, 0.f, 0.f, 0.f}, {0.f, 0.f, 0.f, 0.f}};

    const int srow = tid >> 2;
    const int scol = (tid & 3) * 8;
    const bf16_t* Aptr = A + (size_t)(m0 + srow) * K + scol;
    const float*  Wptr = W + (size_t)(n0 + srow) * K + scol;

    for (int k0 = 0; k0 < K; k0 += 32) {
        *(uint4*)(&As[srow * LDR + scol]) = *(const uint4*)(Aptr + k0);
        float4 w0 = *(const float4*)(Wptr + k0);
        float4 w1 = *(const float4*)(Wptr + k0 + 4);
        bf16x8 wb;
        wb[0] = (bf16_t)w0.x; wb[1] = (bf16_t)w0.y; wb[2] = (bf16_t)w0.z; wb[3] = (bf16_t)w0.w;
        wb[4] = (bf16_t)w1.x; wb[5] = (bf16_t)w1.y; wb[6] = (bf16_t)w1.z; wb[7] = (bf16_t)w1.w;
        *(bf16x8*)(&Bs[srow * LDR + scol]) = wb;
        __syncthreads();
        const bf16x8 a = *(const bf16x8*)(&As[(wave * 16 + ln16) * LDR + q * 8]);
#pragma unroll
        for (int nt = 0; nt < 4; nt++) {
            const bf16x8 b = *(const bf16x8*)(&Bs[(nt * 16 + ln16) * LDR + q * 8]);
            acc[nt] = __builtin_amdgcn_mfma_f32_16x16x32_bf16(a, b, acc[nt], 0, 0, 0);
        }
        __syncthreads();
    }

#pragma unroll
    for (int nt = 0; nt < 4; nt++) {
        const int n = n0 + nt * 16 + ln16;
        float bv = 0.f;
        if constexpr (HAS_BIAS) bv = bias[n];
#pragma unroll
        for (int r = 0; r < 4; r++) {
            const int m = m0 + wave * 16 + q * 4 + r;
            float v = acc[nt][r] + bv;
            if constexpr (RELU) v = fmaxf(v, 0.f);
            if constexpr (HAS_RES) v += res[(size_t)m * N + n];
            C[(size_t)m * N + n] = (OutT)v;
        }
    }
}

// ---------------------------------------------------------------- flash attention
// One block per (q-tile of 64 rows, b*h). 4 waves; wave w owns q rows w*16..w*16+15.
// Q,K,V bf16 [2048, 768]; head slice cols hh*64..+63. Online softmax, MFMA QK^T & PV.
__global__ __launch_bounds__(256) void attn_kernel(const bf16_t* __restrict__ Q,
                                                   const bf16_t* __restrict__ K,
                                                   const bf16_t* __restrict__ V,
                                                   bf16_t* __restrict__ ctx) {
    // LDS: Qs [0,4096) elems (reused as Ps after Q-frag hoist), Ks [4096,8192), Vts [8192,12288)
    __shared__ bf16_t smem[12288];
    bf16_t* Qs  = smem;
    bf16_t* Ks  = smem + 4096;
    bf16_t* Vts = smem + 8192;
    bf16_t* Ps  = smem;                      // aliases Qs (dead after frag hoist)

    const int qt  = blockIdx.x;              // 0..15
    const int bh  = blockIdx.y;              // 0..23
    const int b   = bh / N_HEADS;
    const int hh  = bh - b * N_HEADS;
    const int tid  = threadIdx.x;
    const int wave = tid >> 6;
    const int lane = tid & 63;
    const int quad = lane >> 4;
    const int ln16 = lane & 15;
    const int q0   = qt * 64;
    const size_t base = (size_t)(b * SEQ) * D_MODEL + hh * DK;

    const int r0 = tid >> 3;                 // 0..31 staging row
    const int cg = tid & 7;                  // col group (8 elems)

    // ---- stage Q tile (natural layout), hoist A-frags
    {
        const bf16_t* src = Q + base + (size_t)q0 * D_MODEL;
        *(uint4*)&Qs[r0 * 64 + cg * 8]        = *(const uint4*)(src + (size_t)r0 * D_MODEL + cg * 8);
        *(uint4*)&Qs[(r0 + 32) * 64 + cg * 8] = *(const uint4*)(src + (size_t)(r0 + 32) * D_MODEL + cg * 8);
    }
    __syncthreads();
    const bf16x8 aq0 = *(const bf16x8*)&Qs[(wave * 16 + ln16) * 64 + quad * 8];
    const bf16x8 aq1 = *(const bf16x8*)&Qs[(wave * 16 + ln16) * 64 + 32 + quad * 8];

    float m_run[4] = {-1e30f, -1e30f, -1e30f, -1e30f};
    float l_run[4] = {0.f, 0.f, 0.f, 0.f};
    floatx4 o[4] = {{0.f, 0.f, 0.f, 0.f}, {0.f, 0.f, 0.f, 0.f},
                    {0.f, 0.f, 0.f, 0.f}, {0.f, 0.f, 0.f, 0.f}};
    const float scale = 0.125f;              // 1/sqrt(64)

    for (int j0 = 0; j0 <= q0; j0 += 64) {
        __syncthreads();                     // prev iter's reads done before restage (iter0: Q-frags hoisted)
        // ---- stage K (natural) and V (transposed + xor-swizzled)
        const bf16_t* ksrc = K + base + (size_t)j0 * D_MODEL;
        const bf16_t* vsrc = V + base + (size_t)j0 * D_MODEL;
#pragma unroll
        for (int half = 0; half < 2; half++) {
            const int j = r0 + half * 32;
            *(uint4*)&Ks[j * 64 + cg * 8] = *(const uint4*)(ksrc + (size_t)j * D_MODEL + cg * 8);
            const bf16x8 vv = *(const bf16x8*)(vsrc + (size_t)j * D_MODEL + cg * 8);
#pragma unroll
            for (int i = 0; i < 8; i++) {
                const int d = cg * 8 + i;
                Vts[d * 64 + (((j >> 3) ^ cg) << 3) + (j & 7)] = vv[i];
            }
        }
        __syncthreads();

        // ---- S = (Q K^T) * scale   (C-layout: row=quad*4+r, col=nt*16+ln16)
        floatx4 s[4];
#pragma unroll
        for (int nt = 0; nt < 4; nt++) {
            const bf16x8 bk0 = *(const bf16x8*)&Ks[(nt * 16 + ln16) * 64 + quad * 8];
            const bf16x8 bk1 = *(const bf16x8*)&Ks[(nt * 16 + ln16) * 64 + 32 + quad * 8];
            floatx4 z = {0.f, 0.f, 0.f, 0.f};
            z = __builtin_amdgcn_mfma_f32_16x16x32_bf16(aq0, bk0, z, 0, 0, 0);
            z = __builtin_amdgcn_mfma_f32_16x16x32_bf16(aq1, bk1, z, 0, 0, 0);
            s[nt] = z;
        }
        const bool diag = (j0 == q0);
#pragma unroll
        for (int nt = 0; nt < 4; nt++)
#pragma unroll
            for (int r = 0; r < 4; r++) {
                float v = s[nt][r] * scale;
                if (diag && (nt * 16 + ln16 > wave * 16 + quad * 4 + r)) v = -1e30f;
                s[nt][r] = v;
            }

        // ---- online softmax update (rows quad*4+r; reduce over 16 lanes)
        float alpha[4];
#pragma unroll
        for (int r = 0; r < 4; r++) {
            float v = fmaxf(fmaxf(s[0][r], s[1][r]), fmaxf(s[2][r], s[3][r]));
#pragma unroll
            for (int off = 1; off < 16; off <<= 1) v = fmaxf(v, __shfl_xor(v, off, 64));
            const float m_new = fmaxf(m_run[r], v);
            alpha[r] = __expf(m_run[r] - m_new);
            m_run[r] = m_new;
        }
        float rsum[4] = {0.f, 0.f, 0.f, 0.f};
#pragma unroll
        for (int nt = 0; nt < 4; nt++)
#pragma unroll
            for (int r = 0; r < 4; r++) {
                const float p = __expf(s[nt][r] - m_run[r]);
                s[nt][r] = p;
                rsum[r] += p;
            }
#pragma unroll
        for (int r = 0; r < 4; r++) {
            float v = rsum[r];
#pragma unroll
            for (int off = 1; off < 16; off <<= 1) v += __shfl_xor(v, off, 64);
            l_run[r] = l_run[r] * alpha[r] + v;
        }
#pragma unroll
        for (int nt = 0; nt < 4; nt++)
#pragma unroll
            for (int r = 0; r < 4; r++) o[nt][r] *= alpha[r];

        // ---- P: C-layout regs -> per-wave LDS (xor-swizzled) -> A-layout frags
        bf16_t* Pw = Ps + wave * 1024;
#pragma unroll
        for (int nt = 0; nt < 4; nt++)
#pragma unroll
            for (int r = 0; r < 4; r++) {
                const int rr = quad * 4 + r;
                Pw[rr * 64 + (((nt * 2 + (ln16 >> 3)) ^ (rr & 7)) << 3) + (ln16 & 7)] = (bf16_t)s[nt][r];
            }
        const bf16x8 ap0 = *(const bf16x8*)&Pw[ln16 * 64 + ((quad ^ (ln16 & 7)) << 3)];
        const bf16x8 ap1 = *(const bf16x8*)&Pw[ln16 * 64 + (((quad + 4) ^ (ln16 & 7)) << 3)];

        // ---- O += P V   (B-frag from swizzled Vt: row d, k=j)
#pragma unroll
        for (int nt = 0; nt < 4; nt++) {
            const int d  = nt * 16 + ln16;
            const int dd = (nt * 2 + (ln16 >> 3)) & 7;
            const bf16x8 bv0 = *(const bf16x8*)&Vts[d * 64 + ((quad ^ dd) << 3)];
            const bf16x8 bv1 = *(const bf16x8*)&Vts[d * 64 + (((quad + 4) ^ dd) << 3)];
            o[nt] = __builtin_amdgcn_mfma_f32_16x16x32_bf16(ap0, bv0, o[nt], 0, 0, 0);
            o[nt] = __builtin_amdgcn_mfma_f32_16x16x32_bf16(ap1, bv1, o[nt], 0, 0, 0);
        }
    }

    // ---- epilogue: O / l -> ctx
#pragma unroll
    for (int r = 0; r < 4; r++) {
        const float inv = 1.0f / l_run[r];
        const int m = q0 + wave * 16 + quad * 4 + r;
#pragma unroll
        for (int nt = 0; nt < 4; nt++) {
            ctx[base + (size_t)m * D_MODEL + nt * 16 + ln16] = (bf16_t)(o[nt][r] * inv);
        }
    }
}

// ---------------------------------------------------------------- launch
extern "C" void kernel_launch(void* const* d_in, const int* in_sizes, int n_in,
                              void* d_out, int out_size, void* d_ws, size_t ws_size,
                              hipStream_t stream) {
    const int*   x    = (const int*)d_in[0];
    const float* tok  = (const float*)d_in[1];
    const float* pos  = (const float*)d_in[2];
    const float* Wq   = (const float*)d_in[3];
    const float* bq   = (const float*)d_in[4];
    const float* Wk   = (const float*)d_in[5];
    const float* bk   = (const float*)d_in[6];
    const float* Wv   = (const float*)d_in[7];
    const float* bv   = (const float*)d_in[8];
    const float* Wo   = (const float*)d_in[9];
    const float* bo   = (const float*)d_in[10];
    const float* W1   = (const float*)d_in[11];
    const float* b1   = (const float*)d_in[12];
    const float* W2   = (const float*)d_in[13];
    const float* b2   = (const float*)d_in[14];
    const float* ln1g = (const float*)d_in[15];
    const float* ln1b = (const float*)d_in[16];
    const float* ln2g = (const float*)d_in[17];
    const float* ln2b = (const float*)d_in[18];
    const float* lnfg = (const float*)d_in[19];
    const float* lnfb = (const float*)d_in[20];

    char* ws = (char*)d_ws;
    const size_t OFF_H   = 0;                   // fp32 [2048,768]
    const size_t OFF_Y   = 6291456;             // bf16 [2048,768]
    const size_t OFF_Q   = 9437184;             // bf16 [2048,768]
    const size_t OFF_K   = 12582912;            // bf16 [2048,768]
    const size_t OFF_V   = 15728640;            // bf16 [2048,768]
    const size_t OFF_CTX = 18874368;            // bf16 [2048,768]
    const size_t OFF_FF  = OFF_Q;               // bf16 [2048,3072] aliases Q+K+V+CTX (all dead)

    float*  h    = (float*)(ws + OFF_H);
    bf16_t* y    = (bf16_t*)(ws + OFF_Y);
    bf16_t* qb   = (bf16_t*)(ws + OFF_Q);
    bf16_t* kb   = (bf16_t*)(ws + OFF_K);
    bf16_t* vbuf = (bf16_t*)(ws + OFF_V);
    bf16_t* ctx  = (bf16_t*)(ws + OFF_CTX);
    bf16_t* ff   = (bf16_t*)(ws + OFF_FF);
    float*  outp = (float*)d_out;

    embed_kernel<<<NROWS, 256, 0, stream>>>(x, tok, pos, h);

    const dim3 g768(D_MODEL / 64, NROWS / 64);
    const dim3 gffn(FFN / 64, NROWS / 64);
    const dim3 gvoc(VOCAB / 64, NROWS / 64);
    const dim3 gattn(SEQ / 64, BATCH * N_HEADS);

    for (int l = 0; l < N_LAYERS; l++) {
        const float* Wq_l = Wq + (size_t)l * D_MODEL * D_MODEL;
        const float* Wk_l = Wk + (size_t)l * D_MODEL * D_MODEL;
        const float* Wv_l = Wv + (size_t)l * D_MODEL * D_MODEL;
        const float* Wo_l = Wo + (size_t)l * D_MODEL * D_MODEL;
        const float* W1_l = W1 + (size_t)l * FFN * D_MODEL;
        const float* W2_l = W2 + (size_t)l * D_MODEL * FFN;

        ln_kernel<<<NROWS, 256, 0, stream>>>(h, ln1g + l * D_MODEL, ln1b + l * D_MODEL, y);

        gemm_bt<bf16_t, false, true, false><<<g768, 256, 0, stream>>>(
            y, Wq_l, bq + l * D_MODEL, nullptr, qb, NROWS, D_MODEL, D_MODEL);
        gemm_bt<bf16_t, false, true, false><<<g768, 256, 0, stream>>>(
            y, Wk_l, bk + l * D_MODEL, nullptr, kb, NROWS, D_MODEL, D_MODEL);
        gemm_bt<bf16_t, false, true, false><<<g768, 256, 0, stream>>>(
            y, Wv_l, bv + l * D_MODEL, nullptr, vbuf, NROWS, D_MODEL, D_MODEL);

        attn_kernel<<<gattn, 256, 0, stream>>>(qb, kb, vbuf, ctx);

        gemm_bt<float, false, true, true><<<g768, 256, 0, stream>>>(
            ctx, Wo_l, bo + l * D_MODEL, h, h, NROWS, D_MODEL, D_MODEL);

        ln_kernel<<<NROWS, 256, 0, stream>>>(h, ln2g + l * D_MODEL, ln2b + l * D_MODEL, y);

        gemm_bt<bf16_t, true, true, false><<<gffn, 256, 0, stream>>>(
            y, W1_l, b1 + l * FFN, nullptr, ff, NROWS, FFN, D_MODEL);

        gemm_bt<float, false, true, true><<<g768, 256, 0, stream>>>(
            ff, W2_l, b2 + l * D_MODEL, h, h, NROWS, D_MODEL, FFN);
    }

    ln_kernel<<<NROWS, 256, 0, stream>>>(h, lnfg, lnfb, y);

    gemm_bt<float, false, false, false><<<gvoc, 256, 0, stream>>>(
        y, tok, nullptr, nullptr, outp, NROWS, VOCAB, D_MODEL);
}